// Round 2
// baseline (558.025 us; speedup 1.0000x reference)
//
#include <hip/hip_runtime.h>
#include <math.h>

#define N_TOK 131072
#define N_E   1024
#define E_DIM 64
#define BETA  0.4

// d_out layout (float32, concatenated in return order):
//   [0, 8388608)           z_q_st
//   [8388608]              vq_loss
//   [8388609, 8519681)     idx (written as float)
//   [8519681]              perplexity
#define ZQ_OFF   0
#define LOSS_OFF 8388608
#define IDX_OFF  8388609
#define PERP_OFF 8519681

// d_ws layout:
//   [0, 4096)       c2 (1024 f32)  -- RN32(exact ||c_e||^2)
//   [4096, 8192)    counts (1024 i32)
//   [8192, 8200)    sum_sq (double)
//   [8200, 8204)    wl_count (int)
//   [8204, ...)     wl (int, flagged token ids)
#define WS_C2    0
#define WS_CNT   4096
#define WS_SSQ   8192
#define WS_WLC   8200
#define WS_WL    8204

__global__ void c2_kernel(const float* __restrict__ cb, float* __restrict__ c2) {
    int e = blockIdx.x * blockDim.x + threadIdx.x;
    if (e < N_E) {
        const float* p = cb + (size_t)e * E_DIM;
        double s = 0.0;
#pragma unroll
        for (int k = 0; k < E_DIM; ++k) {
            double c = (double)p[k];
            s = fma(c, c, s);
        }
        c2[e] = (float)s;   // correctly-rounded f32 ||c||^2 (order error ~1e-12 << grid)
    }
}

__global__ __launch_bounds__(256) void vq_main(
    const float* __restrict__ z, const float* __restrict__ cb,
    const float* __restrict__ c2, int* __restrict__ counts,
    double* __restrict__ sum_sq, int* __restrict__ wl_count,
    int* __restrict__ wl, float margin, float* __restrict__ out) {

    __shared__ float cbs[128 * E_DIM];   // 32 KB codebook chunk
    __shared__ float c2s[128];
    __shared__ double wred[4];

    const int n = blockIdx.x * 256 + threadIdx.x;

    float4 zv[16];
    const float4* zp = (const float4*)(z + (size_t)n * E_DIM);
#pragma unroll
    for (int k = 0; k < 16; ++k) zv[k] = zp[k];

    float min1 = 3.4e38f, min2 = 3.4e38f;
    int best = 0;

    for (int c = 0; c < 8; ++c) {
        __syncthreads();
        const float4* src = (const float4*)(cb + (size_t)c * 128 * E_DIM);
        float4* dst = (float4*)cbs;
#pragma unroll
        for (int r = 0; r < 8; ++r)
            dst[threadIdx.x + 256 * r] = src[threadIdx.x + 256 * r];
        if (threadIdx.x < 128) c2s[threadIdx.x] = c2[c * 128 + threadIdx.x];
        __syncthreads();

        for (int e = 0; e < 128; ++e) {
            const float4* cp = (const float4*)(cbs + e * E_DIM);
            float acc = 0.f;
#pragma unroll
            for (int k = 0; k < 16; ++k) {
                float4 cv = cp[k];   // wave-uniform address -> LDS broadcast
                acc = fmaf(zv[k].x, cv.x, acc);
                acc = fmaf(zv[k].y, cv.y, acc);
                acc = fmaf(zv[k].z, cv.z, acc);
                acc = fmaf(zv[k].w, cv.w, acc);
            }
            float t = fmaf(-2.f, acc, c2s[e]);   // screen metric: ||c||^2 - 2 z.c
            int ge = c * 128 + e;
            if (t < min1) { min2 = min1; min1 = t; best = ge; }
            else if (t < min2) { min2 = t; }
        }
    }

    // Ambiguous under the reference's f32 quantization (d rounds on a ~ulp(||z||^2)
    // grid): defer to exact-f32-semantics fixup kernel.
    bool flagged = (min2 - min1) < margin;

    float ls = 0.f;
    if (flagged) {
        int pos = atomicAdd(wl_count, 1);
        wl[pos] = n;
    } else {
        const float4* cbest = (const float4*)(cb + (size_t)best * E_DIM);
        float4* outq = (float4*)(out + ZQ_OFF + (size_t)n * E_DIM);
#pragma unroll
        for (int k = 0; k < 16; ++k) {
            float4 cv = cbest[k];
            float dx = cv.x - zv[k].x;
            float dy = cv.y - zv[k].y;
            float dz = cv.z - zv[k].z;
            float dw = cv.w - zv[k].w;
            ls = fmaf(dx, dx, ls);
            ls = fmaf(dy, dy, ls);
            ls = fmaf(dz, dz, ls);
            ls = fmaf(dw, dw, ls);
            float4 q;
            q.x = zv[k].x + dx;
            q.y = zv[k].y + dy;
            q.z = zv[k].z + dz;
            q.w = zv[k].w + dw;
            outq[k] = q;
        }
        out[IDX_OFF + n] = (float)best;
        atomicAdd(&counts[best], 1);
    }

    double dl = (double)ls;
#pragma unroll
    for (int off = 32; off > 0; off >>= 1)
        dl += __shfl_down(dl, off, 64);
    int lane = threadIdx.x & 63, w = threadIdx.x >> 6;
    if (lane == 0) wred[w] = dl;
    __syncthreads();
    if (threadIdx.x == 0) {
        double s = wred[0] + wred[1] + wred[2] + wred[3];
        atomicAdd(sum_sq, s);
    }
}

// Exact replication of numpy f32 semantics for flagged tokens:
//   q = RN32(z*z); z2 = numpy scalar pairwise (8 accumulators, tree combine)
//   m32 = RN32(exact z.c); d = RN32( RN32(z2 + c2) - RN32(2*m32) )
//   argmin with lowest-index tie-break (np.argmin).
__global__ __launch_bounds__(256) void vq_fixup(
    const float* __restrict__ z, const float* __restrict__ cb,
    const float* __restrict__ c2, const int* __restrict__ wl,
    const int* __restrict__ wl_count, int* __restrict__ counts,
    double* __restrict__ sum_sq, float* __restrict__ out) {

    __shared__ float zs[E_DIM];
    __shared__ float z2s;
    __shared__ unsigned long long red[256];

    const int count = *wl_count;
    for (int w = blockIdx.x; w < count; w += gridDim.x) {
        const int n = wl[w];
        __syncthreads();   // protect zs/red reuse across iterations
        if (threadIdx.x < E_DIM) zs[threadIdx.x] = z[(size_t)n * E_DIM + threadIdx.x];
        __syncthreads();
        if (threadIdx.x == 0) {
            float r[8];
#pragma unroll
            for (int j = 0; j < 8; ++j) r[j] = __fmul_rn(zs[j], zs[j]);
#pragma unroll
            for (int i = 8; i < 64; i += 8)
#pragma unroll
                for (int j = 0; j < 8; ++j)
                    r[j] = __fadd_rn(r[j], __fmul_rn(zs[i + j], zs[i + j]));
            float s01 = __fadd_rn(r[0], r[1]);
            float s23 = __fadd_rn(r[2], r[3]);
            float s45 = __fadd_rn(r[4], r[5]);
            float s67 = __fadd_rn(r[6], r[7]);
            z2s = __fadd_rn(__fadd_rn(s01, s23), __fadd_rn(s45, s67));
        }
        __syncthreads();
        const float z2 = z2s;

        unsigned long long bestkey = ~0ull;
        for (int e = threadIdx.x; e < N_E; e += 256) {
            const float* cp = cb + (size_t)e * E_DIM;
            double m = 0.0;
#pragma unroll
            for (int i = 0; i < E_DIM; ++i)
                m = fma((double)zs[i], (double)cp[i], m);
            float m32 = (float)m;
            float d = __fsub_rn(__fadd_rn(z2, c2[e]), __fmul_rn(2.0f, m32));
            // d > 0 always (d ~ ||z||^2): float bits are order-isomorphic
            unsigned long long key =
                ((unsigned long long)__float_as_uint(d) << 32) | (unsigned)e;
            if (key < bestkey) bestkey = key;
        }
        red[threadIdx.x] = bestkey;
        __syncthreads();
        for (int s = 128; s > 0; s >>= 1) {
            if (threadIdx.x < s && red[threadIdx.x + s] < red[threadIdx.x])
                red[threadIdx.x] = red[threadIdx.x + s];
            __syncthreads();
        }
        const int best = (int)(red[0] & 0xffffffffu);

        if (threadIdx.x < E_DIM) {   // wave 0
            float cv = cb[(size_t)best * E_DIM + threadIdx.x];
            float zi = zs[threadIdx.x];
            float diff = cv - zi;
            out[ZQ_OFF + (size_t)n * E_DIM + threadIdx.x] = zi + diff;
            double d2 = (double)diff * (double)diff;
#pragma unroll
            for (int off = 32; off > 0; off >>= 1)
                d2 += __shfl_down(d2, off, 64);
            if (threadIdx.x == 0) {
                atomicAdd(sum_sq, d2);
                atomicAdd(&counts[best], 1);
                out[IDX_OFF + n] = (float)best;
            }
        }
    }
}

__global__ __launch_bounds__(1024) void finalize_kernel(
    const int* __restrict__ counts, const double* __restrict__ sum_sq,
    float* __restrict__ out) {
    __shared__ double red[1024];
    int e = threadIdx.x;
    double em = (double)counts[e] / (double)N_TOK;
    red[e] = -em * log(em + 1e-10);
    __syncthreads();
    for (int s = 512; s > 0; s >>= 1) {
        if (e < s) red[e] += red[e + s];
        __syncthreads();
    }
    if (e == 0) {
        double usage = red[0];
        double mse = sum_sq[0] / (double)((size_t)N_TOK * E_DIM);
        out[LOSS_OFF] = (float)((1.0 + BETA) * mse + 0.01 * usage);
        out[PERP_OFF] = (float)exp(usage);
    }
}

extern "C" void kernel_launch(void* const* d_in, const int* in_sizes, int n_in,
                              void* d_out, int out_size, void* d_ws, size_t ws_size,
                              hipStream_t stream) {
    const float* z  = (const float*)d_in[0];
    const float* cb = (const float*)d_in[1];
    float* out = (float*)d_out;

    float*  c2     = (float*)((char*)d_ws + WS_C2);
    int*    counts = (int*)((char*)d_ws + WS_CNT);
    double* sum_sq = (double*)((char*)d_ws + WS_SSQ);
    int*    wlc    = (int*)((char*)d_ws + WS_WLC);
    int*    wl     = (int*)((char*)d_ws + WS_WL);

    // worklist worst case 131072 ints; if ws too small, disable flagging (degraded
    // accuracy, but no corruption)
    float margin = (ws_size >= (size_t)(WS_WL + 4 * N_TOK)) ? 4e-5f : 0.0f;

    hipMemsetAsync((char*)d_ws + WS_CNT, 0, WS_WLC + 4 - WS_CNT, stream);

    c2_kernel<<<4, 256, 0, stream>>>(cb, c2);
    vq_main<<<512, 256, 0, stream>>>(z, cb, c2, counts, sum_sq, wlc, wl, margin, out);
    vq_fixup<<<1024, 256, 0, stream>>>(z, cb, c2, wl, wlc, counts, sum_sq, out);
    finalize_kernel<<<1, 1024, 0, stream>>>(counts, sum_sq, out);
}

// Round 3
// 343.811 us; speedup vs baseline: 1.6231x; 1.6231x over previous
//
#include <hip/hip_runtime.h>
#include <math.h>

#define N_TOK 131072
#define N_E   1024
#define E_DIM 64
#define BETA  0.4

// d_out layout (float32, concatenated in return order):
//   [0, 8388608)           z_q_st
//   [8388608]              vq_loss
//   [8388609, 8519681)     idx (written as float)
//   [8519681]              perplexity
#define ZQ_OFF   0
#define LOSS_OFF 8388608
#define IDX_OFF  8388609
#define PERP_OFF 8519681

// d_ws layout (total 409600 B; round-2 pass proves ws_size >= 532540):
#define WS_C2    0        // 1024 f32: RN32(exact ||c_e||^2)
#define WS_CNT   4096     // 1024 i32 counts
#define WS_SSQ   8192     // double sum_sq
#define WS_FLAGS 16384    // 131072 bytes: per-token ambiguity flag
#define WS_FHI   147456   // 131072 B: codebook bf16-hi, MFMA B-frag layout
#define WS_FLO   278528   // 131072 B: codebook bf16-lo, MFMA B-frag layout

typedef short bf16x8 __attribute__((ext_vector_type(8)));
typedef float f32x4  __attribute__((ext_vector_type(4)));

__device__ inline unsigned short f32_to_bf16_rn(float f) {
    unsigned u = __float_as_uint(f);
    unsigned r = (u + 0x7fffu + ((u >> 16) & 1u)) >> 16;  // round-to-nearest-even
    return (unsigned short)r;
}
__device__ inline float bf16_to_f32(unsigned short h) {
    return __uint_as_float(((unsigned)h) << 16);
}

__global__ void c2_kernel(const float* __restrict__ cb, float* __restrict__ c2) {
    int e = blockIdx.x * blockDim.x + threadIdx.x;
    if (e < N_E) {
        const float* p = cb + (size_t)e * E_DIM;
        double s = 0.0;
#pragma unroll
        for (int k = 0; k < E_DIM; ++k) {
            double c = (double)p[k];
            s = fma(c, c, s);
        }
        c2[e] = (float)s;
    }
}

// Pre-swizzle codebook into MFMA B-operand fragment layout (bf16 hi/lo split).
// Fragment element j of lane l, chunk c (16 codes), k-chunk kc:
//   cb[c*16 + (l&15)][kc*32 + (l>>4)*8 + j]
// stored at flat index ((c*2+kc)*64 + l)*8 + j  -> wave loads lane*16B, coalesced.
__global__ void frag_kernel(const float* __restrict__ cb,
                            unsigned short* __restrict__ fhi,
                            unsigned short* __restrict__ flo) {
    int tid = blockIdx.x * 256 + threadIdx.x;   // 65536 total
    int j  = tid & 7;
    int l  = (tid >> 3) & 63;
    int cc = tid >> 9;               // c*2 + kc
    int code = (cc >> 1) * 16 + (l & 15);
    int k    = (cc & 1) * 32 + (l >> 4) * 8 + j;
    float f = cb[(size_t)code * E_DIM + k];
    unsigned short h = f32_to_bf16_rn(f);
    unsigned short lo = f32_to_bf16_rn(f - bf16_to_f32(h));
    fhi[tid] = h;
    flo[tid] = lo;
}

// Screen + epilogue. Block = 256 threads = 4 waves; wave owns 64 tokens
// (4 MFMA 16x16 tiles). Dot via 3-way bf16-split MFMA (error ~2e-6 << margin).
__global__ __launch_bounds__(256) void vq_main(
    const float* __restrict__ z, const float* __restrict__ cb,
    const float* __restrict__ c2, const unsigned short* __restrict__ fhi_,
    const unsigned short* __restrict__ flo_, int* __restrict__ counts,
    double* __restrict__ sum_sq, unsigned char* __restrict__ flags,
    float margin, float* __restrict__ out) {

    __shared__ float c2s[N_E];
    __shared__ int   best_s[256];
    __shared__ unsigned char flag_s[256];
    __shared__ double wred[4];

    const int tid  = threadIdx.x;
    const int lane = tid & 63;
    const int wid  = tid >> 6;
    const int col  = lane & 15;
    const int quad = lane >> 4;
    const int blk_tok0 = blockIdx.x * 256;
    const int wave_tok0 = blk_tok0 + wid * 64;

    // stage c2 into LDS
#pragma unroll
    for (int i = 0; i < 4; ++i) c2s[tid * 4 + i] = c2[tid * 4 + i];

    // ---- A fragments: 4 tiles x 2 k-chunks, bf16 hi/lo (64 VGPRs) ----
    bf16x8 Ah[4][2], Al[4][2];
#pragma unroll
    for (int m = 0; m < 4; ++m) {
        const float* zr = z + (size_t)(wave_tok0 + m * 16 + col) * E_DIM + quad * 8;
#pragma unroll
        for (int kc = 0; kc < 2; ++kc) {
            float4 u0 = *(const float4*)(zr + kc * 32);
            float4 u1 = *(const float4*)(zr + kc * 32 + 4);
            float f[8] = {u0.x, u0.y, u0.z, u0.w, u1.x, u1.y, u1.z, u1.w};
            union { unsigned short u[8]; bf16x8 v; } h, lo;
#pragma unroll
            for (int j = 0; j < 8; ++j) {
                h.u[j]  = f32_to_bf16_rn(f[j]);
                lo.u[j] = f32_to_bf16_rn(f[j] - bf16_to_f32(h.u[j]));
            }
            Ah[m][kc] = h.v;
            Al[m][kc] = lo.v;
        }
    }

    float m1[4][4], m2[4][4];
    int   bi[4][4];
#pragma unroll
    for (int m = 0; m < 4; ++m)
#pragma unroll
        for (int r = 0; r < 4; ++r) { m1[m][r] = 3.4e38f; m2[m][r] = 3.4e38f; bi[m][r] = 0; }

    const uint4* fhi = (const uint4*)fhi_;   // one fragment = 16 B = uint4
    const uint4* flo = (const uint4*)flo_;

    __syncthreads();   // c2s ready

    // ---- screen loop: 64 chunks of 16 codes ----
    for (int c = 0; c < 64; ++c) {
        int fi = (c * 2) * 64 + lane;
        union { uint4 u; bf16x8 v; } bh0, bh1, bl0, bl1;
        bh0.u = fhi[fi];  bh1.u = fhi[fi + 64];
        bl0.u = flo[fi];  bl1.u = flo[fi + 64];
        float c2v = c2s[c * 16 + col];
        int code = c * 16 + col;
#pragma unroll
        for (int m = 0; m < 4; ++m) {
            f32x4 acc = {0.f, 0.f, 0.f, 0.f};
            acc = __builtin_amdgcn_mfma_f32_16x16x32_bf16(Ah[m][0], bh0.v, acc, 0, 0, 0);
            acc = __builtin_amdgcn_mfma_f32_16x16x32_bf16(Ah[m][1], bh1.v, acc, 0, 0, 0);
            acc = __builtin_amdgcn_mfma_f32_16x16x32_bf16(Ah[m][0], bl0.v, acc, 0, 0, 0);
            acc = __builtin_amdgcn_mfma_f32_16x16x32_bf16(Ah[m][1], bl1.v, acc, 0, 0, 0);
            acc = __builtin_amdgcn_mfma_f32_16x16x32_bf16(Al[m][0], bh0.v, acc, 0, 0, 0);
            acc = __builtin_amdgcn_mfma_f32_16x16x32_bf16(Al[m][1], bh1.v, acc, 0, 0, 0);
#pragma unroll
            for (int r = 0; r < 4; ++r) {
                float t = fmaf(-2.f, acc[r], c2v);
                bool lt = t < m1[m][r];
                m2[m][r] = fminf(m2[m][r], fmaxf(m1[m][r], t));  // top-2, old m1
                m1[m][r] = fminf(m1[m][r], t);
                bi[m][r] = lt ? code : bi[m][r];
            }
        }
    }

    // ---- cross-lane merge over the 16 column-lanes of each row ----
#pragma unroll
    for (int m = 0; m < 4; ++m)
#pragma unroll
        for (int r = 0; r < 4; ++r) {
#pragma unroll
            for (int d = 1; d < 16; d <<= 1) {
                float o1 = __shfl_xor(m1[m][r], d, 64);
                float o2 = __shfl_xor(m2[m][r], d, 64);
                int   ob = __shfl_xor(bi[m][r], d, 64);
                float n2 = fminf(fminf(m2[m][r], o2), fmaxf(m1[m][r], o1));
                bool take = (o1 < m1[m][r]) ||
                            (o1 == m1[m][r] && ob < bi[m][r]);
                m1[m][r] = fminf(m1[m][r], o1);
                bi[m][r] = take ? ob : bi[m][r];
                m2[m][r] = n2;
            }
        }

    if (col == 0) {   // lanes 0,16,32,48: own rows quad*4+r of each tile
#pragma unroll
        for (int m = 0; m < 4; ++m)
#pragma unroll
            for (int r = 0; r < 4; ++r) {
                int tl = wid * 64 + m * 16 + quad * 4 + r;
                int n  = blk_tok0 + tl;
                int best = bi[m][r];
                bool fl = (m2[m][r] - m1[m][r]) < margin;
                best_s[tl] = best;
                flag_s[tl] = fl ? 1 : 0;
                flags[n]   = fl ? 1 : 0;
                if (!fl) {
                    out[IDX_OFF + n] = (float)best;
                    atomicAdd(&counts[best], 1);
                }
            }
    }
    __syncthreads();

    // ---- epilogue: coalesced z_q / loss for unflagged tokens ----
    const int sub = tid & 15, grp = tid >> 4;
    double dl = 0.0;
    const float4* zrow = (const float4*)z;
    const float4* crow = (const float4*)cb;
    float4* qrow = (float4*)(out + ZQ_OFF);
#pragma unroll
    for (int p = 0; p < 16; ++p) {
        int tl = p * 16 + grp;
        if (!flag_s[tl]) {
            int n = blk_tok0 + tl;
            float4 z4 = zrow[(size_t)n * 16 + sub];
            float4 c4 = crow[(size_t)best_s[tl] * 16 + sub];
            float dx = c4.x - z4.x, dy = c4.y - z4.y;
            float dz = c4.z - z4.z, dw = c4.w - z4.w;
            float4 q;
            q.x = z4.x + dx; q.y = z4.y + dy;
            q.z = z4.z + dz; q.w = z4.w + dw;
            qrow[(size_t)n * 16 + sub] = q;
            dl += (double)dx * dx + (double)dy * dy
                + (double)dz * dz + (double)dw * dw;
        }
    }
#pragma unroll
    for (int off = 32; off > 0; off >>= 1)
        dl += __shfl_down(dl, off, 64);
    if (lane == 0) wred[wid] = dl;
    __syncthreads();
    if (tid == 0)
        atomicAdd(sum_sq, wred[0] + wred[1] + wred[2] + wred[3]);
}

// Exact numpy-f32 semantics for flagged tokens (verified in round 2):
//   z2 = numpy pairwise (8 accumulators + tree), m32 = RN32(exact z.c),
//   d = RN32(RN32(z2 + c2) - RN32(2*m32)), argmin lowest-index tie-break.
__global__ __launch_bounds__(256) void vq_fixup(
    const float* __restrict__ z, const float* __restrict__ cb,
    const float* __restrict__ c2, const unsigned char* __restrict__ flags,
    int* __restrict__ counts, double* __restrict__ sum_sq,
    float* __restrict__ out) {

    __shared__ float zs[E_DIM];
    __shared__ float z2s;
    __shared__ unsigned long long red[256];

    const int blk_tok0 = blockIdx.x * 256;
    for (int t = 0; t < 256; ++t) {
        if (!flags[blk_tok0 + t]) continue;   // uniform across block
        const int n = blk_tok0 + t;
        __syncthreads();
        if (threadIdx.x < E_DIM) zs[threadIdx.x] = z[(size_t)n * E_DIM + threadIdx.x];
        __syncthreads();
        if (threadIdx.x == 0) {
            float r[8];
#pragma unroll
            for (int j = 0; j < 8; ++j) r[j] = __fmul_rn(zs[j], zs[j]);
#pragma unroll
            for (int i = 8; i < 64; i += 8)
#pragma unroll
                for (int j = 0; j < 8; ++j)
                    r[j] = __fadd_rn(r[j], __fmul_rn(zs[i + j], zs[i + j]));
            float s01 = __fadd_rn(r[0], r[1]);
            float s23 = __fadd_rn(r[2], r[3]);
            float s45 = __fadd_rn(r[4], r[5]);
            float s67 = __fadd_rn(r[6], r[7]);
            z2s = __fadd_rn(__fadd_rn(s01, s23), __fadd_rn(s45, s67));
        }
        __syncthreads();
        const float z2 = z2s;

        unsigned long long bestkey = ~0ull;
        for (int e = threadIdx.x; e < N_E; e += 256) {
            const float* cp = cb + (size_t)e * E_DIM;
            double m = 0.0;
#pragma unroll
            for (int i = 0; i < E_DIM; ++i)
                m = fma((double)zs[i], (double)cp[i], m);
            float m32 = (float)m;
            float d = __fsub_rn(__fadd_rn(z2, c2[e]), __fmul_rn(2.0f, m32));
            unsigned long long key =
                ((unsigned long long)__float_as_uint(d) << 32) | (unsigned)e;
            if (key < bestkey) bestkey = key;
        }
        red[threadIdx.x] = bestkey;
        __syncthreads();
        for (int s = 128; s > 0; s >>= 1) {
            if (threadIdx.x < s && red[threadIdx.x + s] < red[threadIdx.x])
                red[threadIdx.x] = red[threadIdx.x + s];
            __syncthreads();
        }
        const int best = (int)(red[0] & 0xffffffffu);

        if (threadIdx.x < E_DIM) {   // wave 0
            float cv = cb[(size_t)best * E_DIM + threadIdx.x];
            float zi = zs[threadIdx.x];
            float diff = cv - zi;
            out[ZQ_OFF + (size_t)n * E_DIM + threadIdx.x] = zi + diff;
            double d2 = (double)diff * (double)diff;
#pragma unroll
            for (int off = 32; off > 0; off >>= 1)
                d2 += __shfl_down(d2, off, 64);
            if (threadIdx.x == 0) {
                atomicAdd(sum_sq, d2);
                atomicAdd(&counts[best], 1);
                out[IDX_OFF + n] = (float)best;
            }
        }
    }
}

__global__ __launch_bounds__(1024) void finalize_kernel(
    const int* __restrict__ counts, const double* __restrict__ sum_sq,
    float* __restrict__ out) {
    __shared__ double red[1024];
    int e = threadIdx.x;
    double em = (double)counts[e] / (double)N_TOK;
    red[e] = -em * log(em + 1e-10);
    __syncthreads();
    for (int s = 512; s > 0; s >>= 1) {
        if (e < s) red[e] += red[e + s];
        __syncthreads();
    }
    if (e == 0) {
        double usage = red[0];
        double mse = sum_sq[0] / (double)((size_t)N_TOK * E_DIM);
        out[LOSS_OFF] = (float)((1.0 + BETA) * mse + 0.01 * usage);
        out[PERP_OFF] = (float)exp(usage);
    }
}

extern "C" void kernel_launch(void* const* d_in, const int* in_sizes, int n_in,
                              void* d_out, int out_size, void* d_ws, size_t ws_size,
                              hipStream_t stream) {
    const float* z  = (const float*)d_in[0];
    const float* cb = (const float*)d_in[1];
    float* out = (float*)d_out;

    float*          c2     = (float*)((char*)d_ws + WS_C2);
    int*            counts = (int*)((char*)d_ws + WS_CNT);
    double*         sum_sq = (double*)((char*)d_ws + WS_SSQ);
    unsigned char*  flags  = (unsigned char*)((char*)d_ws + WS_FLAGS);
    unsigned short* fhi    = (unsigned short*)((char*)d_ws + WS_FHI);
    unsigned short* flo    = (unsigned short*)((char*)d_ws + WS_FLO);

    const float margin = 4e-5f;

    hipMemsetAsync((char*)d_ws + WS_CNT, 0, WS_SSQ + 8 - WS_CNT, stream);

    c2_kernel<<<4, 256, 0, stream>>>(cb, c2);
    frag_kernel<<<256, 256, 0, stream>>>(cb, fhi, flo);
    vq_main<<<512, 256, 0, stream>>>(z, cb, c2, fhi, flo, counts, sum_sq,
                                     flags, margin, out);
    vq_fixup<<<512, 256, 0, stream>>>(z, cb, c2, flags, counts, sum_sq, out);
    finalize_kernel<<<1, 1024, 0, stream>>>(counts, sum_sq, out);
}

// Round 4
// 260.106 us; speedup vs baseline: 2.1454x; 1.3218x over previous
//
#include <hip/hip_runtime.h>
#include <math.h>

#define N_TOK 131072
#define N_E   1024
#define E_DIM 64
#define BETA  0.4

// d_out layout (float32, concatenated in return order):
#define ZQ_OFF   0
#define LOSS_OFF 8388608
#define IDX_OFF  8388609
#define PERP_OFF 8519681

// d_ws layout (round-2 pass proves ws_size >= 532492):
#define WS_C2    0        // 1024 f32: RN32(exact ||c_e||^2)
#define WS_CNT   4096     // 1024 i32 counts
#define WS_SSQ   8192     // double sum_sq
#define WS_WLC   8200     // int worklist count (pad to 8208)
#define WS_FHI   8208     // 131072 B: codebook bf16-hi, MFMA B-frag layout (16-aligned)
#define WS_FLO   139280   // 131072 B: codebook bf16-lo
#define WS_WL    270352   // worklist ints, capacity (ws_size - WS_WL)/4 >= 65535

typedef short bf16x8 __attribute__((ext_vector_type(8)));
typedef float f32x4  __attribute__((ext_vector_type(4)));

__device__ __forceinline__ unsigned short f32_to_bf16_rn(float f) {
    unsigned u = __float_as_uint(f);
    unsigned r = (u + 0x7fffu + ((u >> 16) & 1u)) >> 16;
    return (unsigned short)r;
}
__device__ __forceinline__ float bf16_to_f32(unsigned short h) {
    return __uint_as_float(((unsigned)h) << 16);
}
__device__ __forceinline__ void gl2lds16(const void* g, void* l) {
    __builtin_amdgcn_global_load_lds(
        (const __attribute__((address_space(1))) unsigned int*)g,
        (__attribute__((address_space(3))) unsigned int*)l, 16, 0, 0);
}

__global__ void c2_kernel(const float* __restrict__ cb, float* __restrict__ c2) {
    int e = blockIdx.x * blockDim.x + threadIdx.x;
    if (e < N_E) {
        const float* p = cb + (size_t)e * E_DIM;
        double s = 0.0;
#pragma unroll
        for (int k = 0; k < E_DIM; ++k) {
            double c = (double)p[k];
            s = fma(c, c, s);
        }
        c2[e] = (float)s;
    }
}

// Codebook -> MFMA B-fragment layout (bf16 hi/lo). Element j, lane l, cc=c*2+kc:
//   cb[c*16 + (l&15)][kc*32 + (l>>4)*8 + j] at flat short index (cc*64 + l)*8 + j.
__global__ void frag_kernel(const float* __restrict__ cb,
                            unsigned short* __restrict__ fhi,
                            unsigned short* __restrict__ flo) {
    int tid = blockIdx.x * 256 + threadIdx.x;   // 65536 total
    int j  = tid & 7;
    int l  = (tid >> 3) & 63;
    int cc = tid >> 9;
    int code = (cc >> 1) * 16 + (l & 15);
    int k    = (cc & 1) * 32 + (l >> 4) * 8 + j;
    float f = cb[(size_t)code * E_DIM + k];
    unsigned short h = f32_to_bf16_rn(f);
    unsigned short lo = f32_to_bf16_rn(f - bf16_to_f32(h));
    fhi[tid] = h;
    flo[tid] = lo;
}

// Cold path (worklist overflow only — never taken at observed flag rates).
// Exact numpy-f32 semantics, serial per thread, global reads to avoid VGPR bloat.
__device__ __attribute__((noinline)) int exact_best_serial(
    const float* __restrict__ z, const float* __restrict__ cb,
    const float* __restrict__ c2, int n) {
    const float* zr = z + (size_t)n * E_DIM;
    float r[8];
#pragma unroll
    for (int j = 0; j < 8; ++j) r[j] = __fmul_rn(zr[j], zr[j]);
#pragma unroll 1
    for (int i = 8; i < 64; i += 8)
#pragma unroll
        for (int j = 0; j < 8; ++j)
            r[j] = __fadd_rn(r[j], __fmul_rn(zr[i + j], zr[i + j]));
    float z2 = __fadd_rn(__fadd_rn(__fadd_rn(r[0], r[1]), __fadd_rn(r[2], r[3])),
                         __fadd_rn(__fadd_rn(r[4], r[5]), __fadd_rn(r[6], r[7])));
    unsigned long long bestkey = ~0ull;
#pragma unroll 1
    for (int e = 0; e < N_E; ++e) {
        const float* cp = cb + (size_t)e * E_DIM;
        double m = 0.0;
#pragma unroll 1
        for (int i = 0; i < E_DIM; ++i)
            m = fma((double)zr[i], (double)cp[i], m);
        float d = __fsub_rn(__fadd_rn(z2, c2[e]), __fmul_rn(2.0f, (float)m));
        unsigned long long key =
            ((unsigned long long)__float_as_uint(d) << 32) | (unsigned)e;
        if (key < bestkey) bestkey = key;
    }
    return (int)(bestkey & 0xffffffffu);
}

// Screen: block = 4 waves, wave owns 64 tokens (4 tiles). B-frags double-buffered
// through LDS via global_load_lds; packed-key top-2 tracker.
__global__ __launch_bounds__(256) void vq_main(
    const float* __restrict__ z, const float* __restrict__ cb,
    const float* __restrict__ c2, const unsigned short* __restrict__ fhi_,
    const unsigned short* __restrict__ flo_, int* __restrict__ counts,
    double* __restrict__ sum_sq, int* __restrict__ wl_count,
    int* __restrict__ wl, int wlcap, float margin, float* __restrict__ out) {

    __shared__ unsigned char stagebuf[2][16384];  // [hi 8K | lo 8K] per buffer
    __shared__ float c2s[N_E];                    // c2 + 0.5 (screen offset)
    __shared__ int   best_s[256];
    __shared__ unsigned char flag_s[256];
    __shared__ double wred[4];

    const int tid  = threadIdx.x;
    const int lane = tid & 63;
    const int wid  = tid >> 6;
    const int col  = lane & 15;
    const int quad = lane >> 4;
    const int blk_tok0 = blockIdx.x * 256;
    const int wave_tok0 = blk_tok0 + wid * 64;

#pragma unroll
    for (int i = 0; i < 4; ++i) c2s[tid * 4 + i] = c2[tid * 4 + i] + 0.5f;

    // A fragments: 4 tiles x 2 k-chunks, bf16 hi/lo
    bf16x8 Ah[4][2], Al[4][2];
#pragma unroll
    for (int m = 0; m < 4; ++m) {
        const float* zr = z + (size_t)(wave_tok0 + m * 16 + col) * E_DIM + quad * 8;
#pragma unroll
        for (int kc = 0; kc < 2; ++kc) {
            float4 u0 = *(const float4*)(zr + kc * 32);
            float4 u1 = *(const float4*)(zr + kc * 32 + 4);
            float f[8] = {u0.x, u0.y, u0.z, u0.w, u1.x, u1.y, u1.z, u1.w};
            union { unsigned short u[8]; bf16x8 v; } h, lo;
#pragma unroll
            for (int j = 0; j < 8; ++j) {
                h.u[j]  = f32_to_bf16_rn(f[j]);
                lo.u[j] = f32_to_bf16_rn(f[j] - bf16_to_f32(h.u[j]));
            }
            Ah[m][kc] = h.v;
            Al[m][kc] = lo.v;
        }
    }

    // packed-key top-2: key = (bits(t + 0.5) & ~63) | chunk  (t' in [0.32,0.68] > 0)
    unsigned k1[4][4], k2[4][4];
#pragma unroll
    for (int m = 0; m < 4; ++m)
#pragma unroll
        for (int r = 0; r < 4; ++r) { k1[m][r] = 0xFFFFFFFFu; k2[m][r] = 0xFFFFFFFFu; }

    const char* hsrc0 = (const char*)fhi_;
    const char* lsrc0 = (const char*)flo_;
    auto stage = [&](int s, int b) {
#pragma unroll
        for (int i = 0; i < 2; ++i) {
            gl2lds16(hsrc0 + s * 8192 + i * 4096 + tid * 16,
                     &stagebuf[b][i * 4096 + wid * 1024]);
            gl2lds16(lsrc0 + s * 8192 + i * 4096 + tid * 16,
                     &stagebuf[b][8192 + i * 4096 + wid * 1024]);
        }
    };

    stage(0, 0);
    for (int s = 0; s < 16; ++s) {
        __syncthreads();              // staged data for s ready (vmcnt drained)
        if (s + 1 < 16) stage(s + 1, (s + 1) & 1);
        const unsigned char* hb = &stagebuf[s & 1][0];
        const unsigned char* lb = &stagebuf[s & 1][8192];
#pragma unroll
        for (int cl = 0; cl < 4; ++cl) {
            const int c = s * 4 + cl;
            const int off0 = (cl * 2) * 1024 + lane * 16;
            union { uint4 u; bf16x8 v; } bh0, bh1, bl0, bl1;
            bh0.u = *(const uint4*)(hb + off0);
            bh1.u = *(const uint4*)(hb + off0 + 1024);
            bl0.u = *(const uint4*)(lb + off0);
            bl1.u = *(const uint4*)(lb + off0 + 1024);
            const float c2p5 = c2s[c * 16 + col];
#pragma unroll
            for (int m = 0; m < 4; ++m) {
                f32x4 acc = {0.f, 0.f, 0.f, 0.f};
                acc = __builtin_amdgcn_mfma_f32_16x16x32_bf16(Ah[m][0], bh0.v, acc, 0, 0, 0);
                acc = __builtin_amdgcn_mfma_f32_16x16x32_bf16(Ah[m][1], bh1.v, acc, 0, 0, 0);
                acc = __builtin_amdgcn_mfma_f32_16x16x32_bf16(Ah[m][0], bl0.v, acc, 0, 0, 0);
                acc = __builtin_amdgcn_mfma_f32_16x16x32_bf16(Ah[m][1], bl1.v, acc, 0, 0, 0);
                acc = __builtin_amdgcn_mfma_f32_16x16x32_bf16(Al[m][0], bh0.v, acc, 0, 0, 0);
                acc = __builtin_amdgcn_mfma_f32_16x16x32_bf16(Al[m][1], bh1.v, acc, 0, 0, 0);
#pragma unroll
                for (int r = 0; r < 4; ++r) {
                    float t = fmaf(-2.f, acc[r], c2p5);
                    unsigned key = (__float_as_uint(t) & 0xFFFFFFC0u) | (unsigned)c;
                    unsigned lo2 = max(k1[m][r], key);
                    k2[m][r] = min(k2[m][r], lo2);
                    k1[m][r] = min(k1[m][r], key);
                }
            }
        }
        __syncthreads();
    }

    // merge + decide, per (m,r)
#pragma unroll
    for (int m = 0; m < 4; ++m) {
#pragma unroll
        for (int r = 0; r < 4; ++r) {
            float v1 = __uint_as_float(k1[m][r] & 0xFFFFFFC0u);
            float v2 = __uint_as_float(k2[m][r] & 0xFFFFFFC0u);
            int   b1 = (int)(k1[m][r] & 63u) * 16 + col;
#pragma unroll
            for (int d = 1; d < 16; d <<= 1) {
                float o1 = __shfl_xor(v1, d, 64);
                float o2 = __shfl_xor(v2, d, 64);
                int   ob = __shfl_xor(b1, d, 64);
                float n2 = fminf(fminf(v2, o2), fmaxf(v1, o1));
                bool take = (o1 < v1) || (o1 == v1 && ob < b1);
                v1 = fminf(v1, o1);
                b1 = take ? ob : b1;
                v2 = n2;
            }
            if (col == 0) {
                int tl = wid * 64 + m * 16 + quad * 4 + r;
                int n  = blk_tok0 + tl;
                int best = b1;
                bool fl = (v2 - v1) < margin;
                if (fl) {
                    int pos = atomicAdd(wl_count, 1);
                    if (pos < wlcap) wl[pos] = n;
                    else { best = exact_best_serial(z, cb, c2, n); fl = false; }
                }
                best_s[tl] = best;
                flag_s[tl] = fl ? 1 : 0;
                if (!fl) {
                    out[IDX_OFF + n] = (float)best;
                    atomicAdd(&counts[best], 1);
                }
            }
        }
    }
    __syncthreads();

    // epilogue: coalesced z_q / loss for unflagged tokens
    const int sub = tid & 15, grp = tid >> 4;
    double dl = 0.0;
    const float4* zrow = (const float4*)z;
    const float4* crow = (const float4*)cb;
    float4* qrow = (float4*)(out + ZQ_OFF);
#pragma unroll
    for (int p = 0; p < 16; ++p) {
        int tl = p * 16 + grp;
        if (!flag_s[tl]) {
            int n = blk_tok0 + tl;
            float4 z4 = zrow[(size_t)n * 16 + sub];
            float4 c4 = crow[(size_t)best_s[tl] * 16 + sub];
            float dx = c4.x - z4.x, dy = c4.y - z4.y;
            float dz = c4.z - z4.z, dw = c4.w - z4.w;
            float4 q;
            q.x = z4.x + dx; q.y = z4.y + dy;
            q.z = z4.z + dz; q.w = z4.w + dw;
            qrow[(size_t)n * 16 + sub] = q;
            dl += (double)dx * dx + (double)dy * dy
                + (double)dz * dz + (double)dw * dw;
        }
    }
#pragma unroll
    for (int off = 32; off > 0; off >>= 1)
        dl += __shfl_down(dl, off, 64);
    if (lane == 0) wred[wid] = dl;
    __syncthreads();
    if (tid == 0)
        atomicAdd(sum_sq, wred[0] + wred[1] + wred[2] + wred[3]);
}

// Exact numpy-f32 semantics for worklist tokens (verified in round 2):
//   z2 = numpy pairwise (8 accumulators + tree), m32 = RN32(exact z.c),
//   d = RN32(RN32(z2 + c2) - RN32(2*m32)), argmin lowest-index tie-break.
__global__ __launch_bounds__(256) void vq_fixup(
    const float* __restrict__ z, const float* __restrict__ cb,
    const float* __restrict__ c2, const int* __restrict__ wl,
    const int* __restrict__ wl_count, int wlcap, int* __restrict__ counts,
    double* __restrict__ sum_sq, float* __restrict__ out) {

    __shared__ float zs[E_DIM];
    __shared__ float z2s;
    __shared__ unsigned long long red[256];

    int count = *wl_count;
    if (count > wlcap) count = wlcap;   // overflow tokens were resolved inline
    for (int w = blockIdx.x; w < count; w += gridDim.x) {
        const int n = wl[w];
        __syncthreads();
        if (threadIdx.x < E_DIM) zs[threadIdx.x] = z[(size_t)n * E_DIM + threadIdx.x];
        __syncthreads();
        if (threadIdx.x == 0) {
            float r[8];
#pragma unroll
            for (int j = 0; j < 8; ++j) r[j] = __fmul_rn(zs[j], zs[j]);
#pragma unroll
            for (int i = 8; i < 64; i += 8)
#pragma unroll
                for (int j = 0; j < 8; ++j)
                    r[j] = __fadd_rn(r[j], __fmul_rn(zs[i + j], zs[i + j]));
            float s01 = __fadd_rn(r[0], r[1]);
            float s23 = __fadd_rn(r[2], r[3]);
            float s45 = __fadd_rn(r[4], r[5]);
            float s67 = __fadd_rn(r[6], r[7]);
            z2s = __fadd_rn(__fadd_rn(s01, s23), __fadd_rn(s45, s67));
        }
        __syncthreads();
        const float z2 = z2s;

        unsigned long long bestkey = ~0ull;
        for (int e = threadIdx.x; e < N_E; e += 256) {
            const float* cp = cb + (size_t)e * E_DIM;
            double m = 0.0;
#pragma unroll
            for (int i = 0; i < E_DIM; ++i)
                m = fma((double)zs[i], (double)cp[i], m);
            float m32 = (float)m;
            float d = __fsub_rn(__fadd_rn(z2, c2[e]), __fmul_rn(2.0f, m32));
            unsigned long long key =
                ((unsigned long long)__float_as_uint(d) << 32) | (unsigned)e;
            if (key < bestkey) bestkey = key;
        }
        red[threadIdx.x] = bestkey;
        __syncthreads();
        for (int s = 128; s > 0; s >>= 1) {
            if (threadIdx.x < s && red[threadIdx.x + s] < red[threadIdx.x])
                red[threadIdx.x] = red[threadIdx.x + s];
            __syncthreads();
        }
        const int best = (int)(red[0] & 0xffffffffu);

        if (threadIdx.x < E_DIM) {   // wave 0
            float cv = cb[(size_t)best * E_DIM + threadIdx.x];
            float zi = zs[threadIdx.x];
            float diff = cv - zi;
            out[ZQ_OFF + (size_t)n * E_DIM + threadIdx.x] = zi + diff;
            double d2 = (double)diff * (double)diff;
#pragma unroll
            for (int off = 32; off > 0; off >>= 1)
                d2 += __shfl_down(d2, off, 64);
            if (threadIdx.x == 0) {
                atomicAdd(sum_sq, d2);
                atomicAdd(&counts[best], 1);
                out[IDX_OFF + n] = (float)best;
            }
        }
    }
}

__global__ __launch_bounds__(1024) void finalize_kernel(
    const int* __restrict__ counts, const double* __restrict__ sum_sq,
    float* __restrict__ out) {
    __shared__ double red[1024];
    int e = threadIdx.x;
    double em = (double)counts[e] / (double)N_TOK;
    red[e] = -em * log(em + 1e-10);
    __syncthreads();
    for (int s = 512; s > 0; s >>= 1) {
        if (e < s) red[e] += red[e + s];
        __syncthreads();
    }
    if (e == 0) {
        double usage = red[0];
        double mse = sum_sq[0] / (double)((size_t)N_TOK * E_DIM);
        out[LOSS_OFF] = (float)((1.0 + BETA) * mse + 0.01 * usage);
        out[PERP_OFF] = (float)exp(usage);
    }
}

extern "C" void kernel_launch(void* const* d_in, const int* in_sizes, int n_in,
                              void* d_out, int out_size, void* d_ws, size_t ws_size,
                              hipStream_t stream) {
    const float* z  = (const float*)d_in[0];
    const float* cb = (const float*)d_in[1];
    float* out = (float*)d_out;

    float*          c2     = (float*)((char*)d_ws + WS_C2);
    int*            counts = (int*)((char*)d_ws + WS_CNT);
    double*         sum_sq = (double*)((char*)d_ws + WS_SSQ);
    int*            wlc    = (int*)((char*)d_ws + WS_WLC);
    unsigned short* fhi    = (unsigned short*)((char*)d_ws + WS_FHI);
    unsigned short* flo    = (unsigned short*)((char*)d_ws + WS_FLO);
    int*            wl     = (int*)((char*)d_ws + WS_WL);

    int wlcap = (ws_size > (size_t)WS_WL) ? (int)((ws_size - WS_WL) / 4) : 0;
    float margin = (wlcap > 0) ? 4.5e-5f : 0.0f;

    hipMemsetAsync((char*)d_ws + WS_CNT, 0, WS_FHI - WS_CNT, stream);

    c2_kernel<<<4, 256, 0, stream>>>(cb, c2);
    frag_kernel<<<256, 256, 0, stream>>>(cb, fhi, flo);
    vq_main<<<512, 256, 0, stream>>>(z, cb, c2, fhi, flo, counts, sum_sq,
                                     wlc, wl, wlcap, margin, out);
    vq_fixup<<<1024, 256, 0, stream>>>(z, cb, c2, wl, wlc, wlcap,
                                       counts, sum_sq, out);
    finalize_kernel<<<1, 1024, 0, stream>>>(counts, sum_sq, out);
}

// Round 5
// 226.507 us; speedup vs baseline: 2.4636x; 1.1483x over previous
//
#include <hip/hip_runtime.h>
#include <math.h>

#define N_TOK 131072
#define N_E   1024
#define E_DIM 64
#define BETA  0.4

// d_out layout (float32, concatenated in return order):
#define ZQ_OFF   0
#define LOSS_OFF 8388608
#define IDX_OFF  8388609
#define PERP_OFF 8519681

// d_ws layout (round-2 pass proves ws_size >= 532492; we use 401424):
#define WS_C2    0        // 1024 f32: RN32(exact ||c_e||^2)
#define WS_CNT   4096     // 1024 i32 counts
#define WS_SSQ   8192     // double sum_sq
#define WS_WLC   8200     // int worklist count (+4 pad)
#define WS_FHI   8208     // 131072 B: codebook bf16-hi, MFMA B-frag layout
#define WS_FLO   139280   // 131072 B: codebook bf16-lo
#define WS_WL    270352   // 8192 ints: worklist (flagged token ids)
#define WS_Z2    303120   // 8192 f32: numpy-pairwise z2 per worklist slot
#define WS_KEYS  335888   // 8192 u64: packed (d_bits<<32)|e per worklist slot
#define WLCAP    8192

typedef short bf16x8 __attribute__((ext_vector_type(8)));
typedef float f32x4  __attribute__((ext_vector_type(4)));
typedef unsigned long long u64;

__device__ __forceinline__ unsigned short f32_to_bf16_rn(float f) {
    unsigned u = __float_as_uint(f);
    unsigned r = (u + 0x7fffu + ((u >> 16) & 1u)) >> 16;
    return (unsigned short)r;
}
__device__ __forceinline__ float bf16_to_f32(unsigned short h) {
    return __uint_as_float(((unsigned)h) << 16);
}
__device__ __forceinline__ void gl2lds16(const void* g, void* l) {
    __builtin_amdgcn_global_load_lds(
        (const __attribute__((address_space(1))) unsigned int*)g,
        (__attribute__((address_space(3))) unsigned int*)l, 16, 0, 0);
}

__global__ void c2_kernel(const float* __restrict__ cb, float* __restrict__ c2) {
    int e = blockIdx.x * blockDim.x + threadIdx.x;
    if (e < N_E) {
        const float* p = cb + (size_t)e * E_DIM;
        double s = 0.0;
#pragma unroll
        for (int k = 0; k < E_DIM; ++k) {
            double c = (double)p[k];
            s = fma(c, c, s);
        }
        c2[e] = (float)s;
    }
}

// Codebook -> MFMA B-fragment layout (bf16 hi/lo). Element j, lane l, cc=c*2+kc:
//   cb[c*16 + (l&15)][kc*32 + (l>>4)*8 + j] at flat short index (cc*64 + l)*8 + j.
__global__ void frag_kernel(const float* __restrict__ cb,
                            unsigned short* __restrict__ fhi,
                            unsigned short* __restrict__ flo) {
    int tid = blockIdx.x * 256 + threadIdx.x;   // 65536 total
    int j  = tid & 7;
    int l  = (tid >> 3) & 63;
    int cc = tid >> 9;
    int code = (cc >> 1) * 16 + (l & 15);
    int k    = (cc & 1) * 32 + (l >> 4) * 8 + j;
    float f = cb[(size_t)code * E_DIM + k];
    unsigned short h = f32_to_bf16_rn(f);
    unsigned short lo = f32_to_bf16_rn(f - bf16_to_f32(h));
    fhi[tid] = h;
    flo[tid] = lo;
}

// Cold path (worklist overflow only). Exact numpy-f32 semantics, serial.
__device__ __attribute__((noinline)) int exact_best_serial(
    const float* __restrict__ z, const float* __restrict__ cb,
    const float* __restrict__ c2, int n) {
    const float* zr = z + (size_t)n * E_DIM;
    float r[8];
#pragma unroll
    for (int j = 0; j < 8; ++j) r[j] = __fmul_rn(zr[j], zr[j]);
#pragma unroll 1
    for (int i = 8; i < 64; i += 8)
#pragma unroll
        for (int j = 0; j < 8; ++j)
            r[j] = __fadd_rn(r[j], __fmul_rn(zr[i + j], zr[i + j]));
    float z2 = __fadd_rn(__fadd_rn(__fadd_rn(r[0], r[1]), __fadd_rn(r[2], r[3])),
                         __fadd_rn(__fadd_rn(r[4], r[5]), __fadd_rn(r[6], r[7])));
    u64 bestkey = ~0ull;
#pragma unroll 1
    for (int e = 0; e < N_E; ++e) {
        const float* cp = cb + (size_t)e * E_DIM;
        double m = 0.0;
#pragma unroll 1
        for (int i = 0; i < E_DIM; ++i)
            m = fma((double)zr[i], (double)cp[i], m);
        float d = __fsub_rn(__fadd_rn(z2, c2[e]), __fmul_rn(2.0f, (float)m));
        u64 key = ((u64)__float_as_uint(d) << 32) | (unsigned)e;
        if (key < bestkey) bestkey = key;
    }
    return (int)(bestkey & 0xffffffffu);
}

// Screen: block = 4 waves x 128 tokens (2 tiles/wave) -> 1024 blocks, 4 blocks/CU.
// B-frags double-buffered via global_load_lds; split 4+2 MFMA chains.
__global__ __launch_bounds__(256, 4) void vq_main(
    const float* __restrict__ z, const float* __restrict__ cb,
    const float* __restrict__ c2, const unsigned short* __restrict__ fhi_,
    const unsigned short* __restrict__ flo_, int* __restrict__ counts,
    double* __restrict__ sum_sq, int* __restrict__ wl_count,
    int* __restrict__ wl, float margin, float* __restrict__ out) {

    __shared__ unsigned char stagebuf[2][16384];  // [hi 8K | lo 8K] per buffer
    __shared__ float c2s[N_E];                    // c2 + 0.5 (screen offset)
    __shared__ int   best_s[128];
    __shared__ unsigned char flag_s[128];
    __shared__ double wred[4];

    const int tid  = threadIdx.x;
    const int lane = tid & 63;
    const int wid  = tid >> 6;
    const int col  = lane & 15;
    const int quad = lane >> 4;
    const int blk_tok0 = blockIdx.x * 128;
    const int wave_tok0 = blk_tok0 + wid * 32;

#pragma unroll
    for (int i = 0; i < 4; ++i) c2s[tid * 4 + i] = c2[tid * 4 + i] + 0.5f;

    // A fragments: 2 tiles x 2 k-chunks, bf16 hi/lo
    bf16x8 Ah[2][2], Al[2][2];
#pragma unroll
    for (int m = 0; m < 2; ++m) {
        const float* zr = z + (size_t)(wave_tok0 + m * 16 + col) * E_DIM + quad * 8;
#pragma unroll
        for (int kc = 0; kc < 2; ++kc) {
            float4 u0 = *(const float4*)(zr + kc * 32);
            float4 u1 = *(const float4*)(zr + kc * 32 + 4);
            float f[8] = {u0.x, u0.y, u0.z, u0.w, u1.x, u1.y, u1.z, u1.w};
            union { unsigned short u[8]; bf16x8 v; } h, lo;
#pragma unroll
            for (int j = 0; j < 8; ++j) {
                h.u[j]  = f32_to_bf16_rn(f[j]);
                lo.u[j] = f32_to_bf16_rn(f[j] - bf16_to_f32(h.u[j]));
            }
            Ah[m][kc] = h.v;
            Al[m][kc] = lo.v;
        }
    }

    // packed-key top-2: key = (bits(t + 0.5) & ~63) | chunk  (t' > 0)
    unsigned k1[2][4], k2[2][4];
#pragma unroll
    for (int m = 0; m < 2; ++m)
#pragma unroll
        for (int r = 0; r < 4; ++r) { k1[m][r] = 0xFFFFFFFFu; k2[m][r] = 0xFFFFFFFFu; }

    const char* hsrc0 = (const char*)fhi_;
    const char* lsrc0 = (const char*)flo_;
    auto stage = [&](int s, int b) {
#pragma unroll
        for (int i = 0; i < 2; ++i) {
            gl2lds16(hsrc0 + s * 8192 + i * 4096 + tid * 16,
                     &stagebuf[b][i * 4096 + wid * 1024]);
            gl2lds16(lsrc0 + s * 8192 + i * 4096 + tid * 16,
                     &stagebuf[b][8192 + i * 4096 + wid * 1024]);
        }
    };

    stage(0, 0);
    for (int s = 0; s < 16; ++s) {
        __syncthreads();              // staged data for s ready
        if (s + 1 < 16) stage(s + 1, (s + 1) & 1);
        const unsigned char* hb = &stagebuf[s & 1][0];
        const unsigned char* lb = &stagebuf[s & 1][8192];
#pragma unroll
        for (int cl = 0; cl < 4; ++cl) {
            const int c = s * 4 + cl;
            const int off0 = (cl * 2) * 1024 + lane * 16;
            union { uint4 u; bf16x8 v; } bh0, bh1, bl0, bl1;
            bh0.u = *(const uint4*)(hb + off0);
            bh1.u = *(const uint4*)(hb + off0 + 1024);
            bl0.u = *(const uint4*)(lb + off0);
            bl1.u = *(const uint4*)(lb + off0 + 1024);
            const float c2p5 = c2s[c * 16 + col];
#pragma unroll
            for (int m = 0; m < 2; ++m) {
                f32x4 acc1 = {0.f, 0.f, 0.f, 0.f};   // B-hi chain (4 deep)
                f32x4 acc2 = {0.f, 0.f, 0.f, 0.f};   // B-lo chain (2 deep)
                acc1 = __builtin_amdgcn_mfma_f32_16x16x32_bf16(Ah[m][0], bh0.v, acc1, 0, 0, 0);
                acc2 = __builtin_amdgcn_mfma_f32_16x16x32_bf16(Ah[m][0], bl0.v, acc2, 0, 0, 0);
                acc1 = __builtin_amdgcn_mfma_f32_16x16x32_bf16(Ah[m][1], bh1.v, acc1, 0, 0, 0);
                acc2 = __builtin_amdgcn_mfma_f32_16x16x32_bf16(Ah[m][1], bl1.v, acc2, 0, 0, 0);
                acc1 = __builtin_amdgcn_mfma_f32_16x16x32_bf16(Al[m][0], bh0.v, acc1, 0, 0, 0);
                acc1 = __builtin_amdgcn_mfma_f32_16x16x32_bf16(Al[m][1], bh1.v, acc1, 0, 0, 0);
#pragma unroll
                for (int r = 0; r < 4; ++r) {
                    float t = fmaf(-2.f, acc1[r], fmaf(-2.f, acc2[r], c2p5));
                    unsigned key = (__float_as_uint(t) & 0xFFFFFFC0u) | (unsigned)c;
                    unsigned lo2 = max(k1[m][r], key);
                    k2[m][r] = min(k2[m][r], lo2);
                    k1[m][r] = min(k1[m][r], key);
                }
            }
        }
        __syncthreads();
    }

    // merge + decide, per (m,r)
#pragma unroll
    for (int m = 0; m < 2; ++m) {
#pragma unroll
        for (int r = 0; r < 4; ++r) {
            float v1 = __uint_as_float(k1[m][r] & 0xFFFFFFC0u);
            float v2 = __uint_as_float(k2[m][r] & 0xFFFFFFC0u);
            int   b1 = (int)(k1[m][r] & 63u) * 16 + col;
#pragma unroll
            for (int d = 1; d < 16; d <<= 1) {
                float o1 = __shfl_xor(v1, d, 64);
                float o2 = __shfl_xor(v2, d, 64);
                int   ob = __shfl_xor(b1, d, 64);
                float n2 = fminf(fminf(v2, o2), fmaxf(v1, o1));
                bool take = (o1 < v1) || (o1 == v1 && ob < b1);
                v1 = fminf(v1, o1);
                b1 = take ? ob : b1;
                v2 = n2;
            }
            if (col == 0) {
                int tl = wid * 32 + m * 16 + quad * 4 + r;
                int n  = blk_tok0 + tl;
                int best = b1;
                bool fl = (v2 - v1) < margin;
                if (fl) {
                    int pos = atomicAdd(wl_count, 1);
                    if (pos < WLCAP) wl[pos] = n;
                    else { best = exact_best_serial(z, cb, c2, n); fl = false; }
                }
                best_s[tl] = best;
                flag_s[tl] = fl ? 1 : 0;
                if (!fl) {
                    out[IDX_OFF + n] = (float)best;
                    atomicAdd(&counts[best], 1);
                }
            }
        }
    }
    __syncthreads();

    // epilogue: coalesced z_q / loss for unflagged tokens
    const int sub = tid & 15, grp = tid >> 4;
    double dl = 0.0;
    const float4* zrow = (const float4*)z;
    const float4* crow = (const float4*)cb;
    float4* qrow = (float4*)(out + ZQ_OFF);
#pragma unroll
    for (int p = 0; p < 8; ++p) {
        int tl = p * 16 + grp;
        if (!flag_s[tl]) {
            int n = blk_tok0 + tl;
            float4 z4 = zrow[(size_t)n * 16 + sub];
            float4 c4 = crow[(size_t)best_s[tl] * 16 + sub];
            float dx = c4.x - z4.x, dy = c4.y - z4.y;
            float dz = c4.z - z4.z, dw = c4.w - z4.w;
            float4 q;
            q.x = z4.x + dx; q.y = z4.y + dy;
            q.z = z4.z + dz; q.w = z4.w + dw;
            qrow[(size_t)n * 16 + sub] = q;
            dl += (double)dx * dx + (double)dy * dy
                + (double)dz * dz + (double)dw * dw;
        }
    }
#pragma unroll
    for (int off = 32; off > 0; off >>= 1)
        dl += __shfl_down(dl, off, 64);
    if (lane == 0) wred[wid] = dl;
    __syncthreads();
    if (tid == 0)
        atomicAdd(sum_sq, wred[0] + wred[1] + wred[2] + wred[3]);
}

// numpy-pairwise z2 (8 accumulators + tree) for each worklist token.
__global__ __launch_bounds__(256) void z2_kernel(
    const float* __restrict__ z, const int* __restrict__ wl,
    const int* __restrict__ wl_count, float* __restrict__ z2arr) {
    int idx = blockIdx.x * 256 + threadIdx.x;       // 8192 threads = WLCAP
    int count = *wl_count; if (count > WLCAP) count = WLCAP;
    if (idx >= count) return;
    const float* zr = z + (size_t)wl[idx] * E_DIM;
    float r[8];
#pragma unroll
    for (int j = 0; j < 8; ++j) r[j] = __fmul_rn(zr[j], zr[j]);
#pragma unroll
    for (int i = 8; i < 64; i += 8)
#pragma unroll
        for (int j = 0; j < 8; ++j)
            r[j] = __fadd_rn(r[j], __fmul_rn(zr[i + j], zr[i + j]));
    z2arr[idx] = __fadd_rn(
        __fadd_rn(__fadd_rn(r[0], r[1]), __fadd_rn(r[2], r[3])),
        __fadd_rn(__fadd_rn(r[4], r[5]), __fadd_rn(r[6], r[7])));
}

// Scan: one wave per (64-token group x 32-code slice). Token-per-lane,
// code row is wave-uniform (broadcast load, no gather). Exact f64 dot ->
// numpy-f32 d -> atomicMin of packed (d_bits<<32)|e  (lowest-e tie-break).
__global__ __launch_bounds__(64) void fixup_scan(
    const float* __restrict__ z, const float* __restrict__ cb,
    const float* __restrict__ c2, const int* __restrict__ wl,
    const int* __restrict__ wl_count, const float* __restrict__ z2arr,
    u64* __restrict__ keys) {

    int count = *wl_count; if (count > WLCAP) count = WLCAP;
    const int g = blockIdx.x >> 5;        // token group (64 per group)
    const int s = blockIdx.x & 31;        // code slice (32 codes)
    if (g * 64 >= count) return;
    const int lane = threadIdx.x;
    const int w = g * 64 + lane;
    const bool valid = w < count;
    const int n = wl[valid ? w : g * 64];

    double zd[E_DIM];
    const float4* zp = (const float4*)(z + (size_t)n * E_DIM);
#pragma unroll
    for (int k = 0; k < 16; ++k) {
        float4 v = zp[k];
        zd[4 * k]     = (double)v.x;
        zd[4 * k + 1] = (double)v.y;
        zd[4 * k + 2] = (double)v.z;
        zd[4 * k + 3] = (double)v.w;
    }
    const float z2 = valid ? z2arr[w] : 0.f;

    u64 best = ~0ull;
    const int e0 = s * 32;
    for (int e = e0; e < e0 + 32; ++e) {
        const float* cp = cb + (size_t)e * E_DIM;   // wave-uniform row
        double m = 0.0;
#pragma unroll
        for (int i = 0; i < E_DIM; ++i)
            m = fma(zd[i], (double)cp[i], m);
        float d = __fsub_rn(__fadd_rn(z2, c2[e]), __fmul_rn(2.0f, (float)m));
        u64 key = ((u64)__float_as_uint(d) << 32) | (unsigned)e;
        if (key < best) best = key;
    }
    if (valid) atomicMin(&keys[w], best);
}

// Apply: one wave per worklist token; finish zq/idx/counts/sum_sq.
__global__ __launch_bounds__(256) void fixup_apply(
    const float* __restrict__ z, const float* __restrict__ cb,
    const int* __restrict__ wl, const int* __restrict__ wl_count,
    const u64* __restrict__ keys, int* __restrict__ counts,
    double* __restrict__ sum_sq, float* __restrict__ out) {

    int count = *wl_count; if (count > WLCAP) count = WLCAP;
    const int lane = threadIdx.x & 63;
    const int gw = blockIdx.x * 4 + (threadIdx.x >> 6);   // global wave id
    for (int w = gw; w < count; w += 1024) {
        const int n = wl[w];
        const int best = (int)(keys[w] & 0xffffffffull);
        float cv = cb[(size_t)best * E_DIM + lane];
        float zi = z[(size_t)n * E_DIM + lane];
        float diff = cv - zi;
        out[ZQ_OFF + (size_t)n * E_DIM + lane] = zi + diff;
        double d2 = (double)diff * (double)diff;
#pragma unroll
        for (int off = 32; off > 0; off >>= 1)
            d2 += __shfl_down(d2, off, 64);
        if (lane == 0) {
            atomicAdd(sum_sq, d2);
            atomicAdd(&counts[best], 1);
            out[IDX_OFF + n] = (float)best;
        }
    }
}

__global__ __launch_bounds__(1024) void finalize_kernel(
    const int* __restrict__ counts, const double* __restrict__ sum_sq,
    float* __restrict__ out) {
    __shared__ double red[1024];
    int e = threadIdx.x;
    double em = (double)counts[e] / (double)N_TOK;
    red[e] = -em * log(em + 1e-10);
    __syncthreads();
    for (int s = 512; s > 0; s >>= 1) {
        if (e < s) red[e] += red[e + s];
        __syncthreads();
    }
    if (e == 0) {
        double usage = red[0];
        double mse = sum_sq[0] / (double)((size_t)N_TOK * E_DIM);
        out[LOSS_OFF] = (float)((1.0 + BETA) * mse + 0.01 * usage);
        out[PERP_OFF] = (float)exp(usage);
    }
}

extern "C" void kernel_launch(void* const* d_in, const int* in_sizes, int n_in,
                              void* d_out, int out_size, void* d_ws, size_t ws_size,
                              hipStream_t stream) {
    const float* z  = (const float*)d_in[0];
    const float* cb = (const float*)d_in[1];
    float* out = (float*)d_out;

    float*          c2     = (float*)((char*)d_ws + WS_C2);
    int*            counts = (int*)((char*)d_ws + WS_CNT);
    double*         sum_sq = (double*)((char*)d_ws + WS_SSQ);
    int*            wlc    = (int*)((char*)d_ws + WS_WLC);
    unsigned short* fhi    = (unsigned short*)((char*)d_ws + WS_FHI);
    unsigned short* flo    = (unsigned short*)((char*)d_ws + WS_FLO);
    int*            wl     = (int*)((char*)d_ws + WS_WL);
    float*          z2arr  = (float*)((char*)d_ws + WS_Z2);
    u64*            keys   = (u64*)((char*)d_ws + WS_KEYS);

    float margin = (ws_size >= (size_t)(WS_KEYS + 8 * WLCAP)) ? 4.5e-5f : 0.0f;

    hipMemsetAsync((char*)d_ws + WS_CNT, 0, WS_FHI - WS_CNT, stream);
    hipMemsetAsync((char*)d_ws + WS_KEYS, 0xFF, 8 * WLCAP, stream);

    c2_kernel<<<4, 256, 0, stream>>>(cb, c2);
    frag_kernel<<<256, 256, 0, stream>>>(cb, fhi, flo);
    vq_main<<<1024, 256, 0, stream>>>(z, cb, c2, fhi, flo, counts, sum_sq,
                                      wlc, wl, margin, out);
    z2_kernel<<<32, 256, 0, stream>>>(z, wl, wlc, z2arr);
    fixup_scan<<<4096, 64, 0, stream>>>(z, cb, c2, wl, wlc, z2arr, keys);
    fixup_apply<<<256, 256, 0, stream>>>(z, cb, wl, wlc, keys, counts,
                                         sum_sq, out);
    finalize_kernel<<<1, 1024, 0, stream>>>(counts, sum_sq, out);
}

// Round 6
// 217.982 us; speedup vs baseline: 2.5600x; 1.0391x over previous
//
#include <hip/hip_runtime.h>
#include <math.h>

#define N_TOK 131072
#define N_E   1024
#define E_DIM 64
#define BETA  0.4

// d_out layout (float32, concatenated in return order):
#define ZQ_OFF   0
#define LOSS_OFF 8388608
#define IDX_OFF  8388609
#define PERP_OFF 8519681

// d_ws layout (round-2 pass proves ws_size >= 532492; we use 367 KB):
#define WS_C2    0        // 1024 f32: RN32(exact ||c_e||^2)
#define WS_CNT   4096     // 1024 i32 counts
#define WS_SSQ   8192     // double sum_sq
#define WS_WLC   8200     // int worklist count (+4 pad)
#define WS_FHI   8208     // 131072 B: codebook bf16-hi, MFMA B-frag layout
#define WS_FLO   139280   // 131072 B: codebook bf16-lo
#define WS_WL    270352   // 8192 ints: worklist (flagged token ids)
#define WS_KEYS  303120   // 8192 u64: packed (d_bits<<32)|e per worklist slot
#define WLCAP    8192

typedef short bf16x8 __attribute__((ext_vector_type(8)));
typedef float f32x4  __attribute__((ext_vector_type(4)));
typedef unsigned long long u64;

__device__ __forceinline__ unsigned short f32_to_bf16_rn(float f) {
    unsigned u = __float_as_uint(f);
    unsigned r = (u + 0x7fffu + ((u >> 16) & 1u)) >> 16;
    return (unsigned short)r;
}
__device__ __forceinline__ float bf16_to_f32(unsigned short h) {
    return __uint_as_float(((unsigned)h) << 16);
}
__device__ __forceinline__ void gl2lds16(const void* g, void* l) {
    __builtin_amdgcn_global_load_lds(
        (const __attribute__((address_space(1))) unsigned int*)g,
        (__attribute__((address_space(3))) unsigned int*)l, 16, 0, 0);
}

// c2 + zero-init of counts/wlc/sum_sq (replaces one memset)
__global__ void c2_kernel(const float* __restrict__ cb, float* __restrict__ c2,
                          int* __restrict__ counts, int* __restrict__ wlc,
                          double* __restrict__ sum_sq) {
    int e = blockIdx.x * blockDim.x + threadIdx.x;
    if (e < N_E) {
        const float* p = cb + (size_t)e * E_DIM;
        double s = 0.0;
#pragma unroll
        for (int k = 0; k < E_DIM; ++k) {
            double c = (double)p[k];
            s = fma(c, c, s);
        }
        c2[e] = (float)s;
        counts[e] = 0;
        if (e == 0) { *wlc = 0; *sum_sq = 0.0; }
    }
}

// Codebook -> MFMA B-fragment layout (bf16 hi/lo); also inits keys (replaces memset).
__global__ void frag_kernel(const float* __restrict__ cb,
                            unsigned short* __restrict__ fhi,
                            unsigned short* __restrict__ flo,
                            u64* __restrict__ keys) {
    int tid = blockIdx.x * 256 + threadIdx.x;   // 65536 total
    if (tid < WLCAP) keys[tid] = ~0ull;
    int j  = tid & 7;
    int l  = (tid >> 3) & 63;
    int cc = tid >> 9;
    int code = (cc >> 1) * 16 + (l & 15);
    int k    = (cc & 1) * 32 + (l >> 4) * 8 + j;
    float f = cb[(size_t)code * E_DIM + k];
    unsigned short h = f32_to_bf16_rn(f);
    unsigned short lo = f32_to_bf16_rn(f - bf16_to_f32(h));
    fhi[tid] = h;
    flo[tid] = lo;
}

// Cold path (worklist overflow only). Exact numpy-f32 semantics, serial.
__device__ __attribute__((noinline)) int exact_best_serial(
    const float* __restrict__ z, const float* __restrict__ cb,
    const float* __restrict__ c2, int n) {
    const float* zr = z + (size_t)n * E_DIM;
    float r[8];
#pragma unroll
    for (int j = 0; j < 8; ++j) r[j] = __fmul_rn(zr[j], zr[j]);
#pragma unroll 1
    for (int i = 8; i < 64; i += 8)
#pragma unroll
        for (int j = 0; j < 8; ++j)
            r[j] = __fadd_rn(r[j], __fmul_rn(zr[i + j], zr[i + j]));
    float z2 = __fadd_rn(__fadd_rn(__fadd_rn(r[0], r[1]), __fadd_rn(r[2], r[3])),
                         __fadd_rn(__fadd_rn(r[4], r[5]), __fadd_rn(r[6], r[7])));
    u64 bestkey = ~0ull;
#pragma unroll 1
    for (int e = 0; e < N_E; ++e) {
        const float* cp = cb + (size_t)e * E_DIM;
        double m = 0.0;
#pragma unroll 1
        for (int i = 0; i < E_DIM; ++i)
            m = fma((double)zr[i], (double)cp[i], m);
        float d = __fsub_rn(__fadd_rn(z2, c2[e]), __fmul_rn(2.0f, (float)m));
        u64 key = ((u64)__float_as_uint(d) << 32) | (unsigned)e;
        if (key < bestkey) bestkey = key;
    }
    return (int)(bestkey & 0xffffffffu);
}

// Screen: 1024 blocks x 128 tokens, 4 blocks/CU. Single barrier per stage
// (bottom barrier removed — prefetch(s+1) vs reads of same buffer in stage s-1
// are separated by the top barrier of stage s). c2 folded into acc init:
// track max of u' = dot - c2/2 + 0.25 (>0), key = (bits&~63)|(63-c).
__global__ __launch_bounds__(256, 4) void vq_main(
    const float* __restrict__ z, const float* __restrict__ cb,
    const float* __restrict__ c2, const unsigned short* __restrict__ fhi_,
    const unsigned short* __restrict__ flo_, int* __restrict__ counts,
    double* __restrict__ sum_sq, int* __restrict__ wl_count,
    int* __restrict__ wl, float margin_u, float* __restrict__ out) {

    __shared__ unsigned char stagebuf[2][16384];  // [hi 8K | lo 8K] per buffer
    __shared__ float c2s[N_E];                    // 0.25 - c2/2
    __shared__ int   best_s[128];
    __shared__ unsigned char flag_s[128];
    __shared__ double wred[4];

    const int tid  = threadIdx.x;
    const int lane = tid & 63;
    const int wid  = tid >> 6;
    const int col  = lane & 15;
    const int quad = lane >> 4;
    const int blk_tok0 = blockIdx.x * 128;
    const int wave_tok0 = blk_tok0 + wid * 32;

#pragma unroll
    for (int i = 0; i < 4; ++i)
        c2s[tid * 4 + i] = fmaf(-0.5f, c2[tid * 4 + i], 0.25f);

    // A fragments: 2 tiles x 2 k-chunks, bf16 hi/lo
    bf16x8 Ah[2][2], Al[2][2];
#pragma unroll
    for (int m = 0; m < 2; ++m) {
        const float* zr = z + (size_t)(wave_tok0 + m * 16 + col) * E_DIM + quad * 8;
#pragma unroll
        for (int kc = 0; kc < 2; ++kc) {
            float4 u0 = *(const float4*)(zr + kc * 32);
            float4 u1 = *(const float4*)(zr + kc * 32 + 4);
            float f[8] = {u0.x, u0.y, u0.z, u0.w, u1.x, u1.y, u1.z, u1.w};
            union { unsigned short u[8]; bf16x8 v; } h, lo;
#pragma unroll
            for (int j = 0; j < 8; ++j) {
                h.u[j]  = f32_to_bf16_rn(f[j]);
                lo.u[j] = f32_to_bf16_rn(f[j] - bf16_to_f32(h.u[j]));
            }
            Ah[m][kc] = h.v;
            Al[m][kc] = lo.v;
        }
    }

    // packed-key top-2 MAX tracker
    unsigned k1[2][4], k2[2][4];
#pragma unroll
    for (int m = 0; m < 2; ++m)
#pragma unroll
        for (int r = 0; r < 4; ++r) { k1[m][r] = 0u; k2[m][r] = 0u; }

    const char* hsrc0 = (const char*)fhi_;
    const char* lsrc0 = (const char*)flo_;
    auto stage = [&](int s, int b) {
#pragma unroll
        for (int i = 0; i < 2; ++i) {
            gl2lds16(hsrc0 + s * 8192 + i * 4096 + tid * 16,
                     &stagebuf[b][i * 4096 + wid * 1024]);
            gl2lds16(lsrc0 + s * 8192 + i * 4096 + tid * 16,
                     &stagebuf[b][8192 + i * 4096 + wid * 1024]);
        }
    };

    const f32x4 zero4 = {0.f, 0.f, 0.f, 0.f};
    stage(0, 0);
    for (int s = 0; s < 16; ++s) {
        __syncthreads();              // drains vmcnt -> staged data for s ready
        if (s + 1 < 16) stage(s + 1, (s + 1) & 1);
        const unsigned char* hb = &stagebuf[s & 1][0];
        const unsigned char* lb = &stagebuf[s & 1][8192];
#pragma unroll
        for (int cl = 0; cl < 4; ++cl) {
            const int c = s * 4 + cl;
            const int off0 = (cl * 2) * 1024 + lane * 16;
            union { uint4 u; bf16x8 v; } bh0, bh1, bl0, bl1;
            bh0.u = *(const uint4*)(hb + off0);
            bh1.u = *(const uint4*)(hb + off0 + 1024);
            bl0.u = *(const uint4*)(lb + off0);
            bl1.u = *(const uint4*)(lb + off0 + 1024);
            const float ch = c2s[c * 16 + col];
            const f32x4 cinit = {ch, ch, ch, ch};
            const unsigned ctag = (unsigned)(63 - c);
#pragma unroll
            for (int m = 0; m < 2; ++m) {
                // two independent 3-deep chains; acc1 seeded with 0.25 - c2/2
                f32x4 acc1 = __builtin_amdgcn_mfma_f32_16x16x32_bf16(Ah[m][0], bh0.v, cinit, 0, 0, 0);
                f32x4 acc2 = __builtin_amdgcn_mfma_f32_16x16x32_bf16(Ah[m][1], bh1.v, zero4, 0, 0, 0);
                acc1 = __builtin_amdgcn_mfma_f32_16x16x32_bf16(Ah[m][0], bl0.v, acc1, 0, 0, 0);
                acc2 = __builtin_amdgcn_mfma_f32_16x16x32_bf16(Ah[m][1], bl1.v, acc2, 0, 0, 0);
                acc1 = __builtin_amdgcn_mfma_f32_16x16x32_bf16(Al[m][0], bh0.v, acc1, 0, 0, 0);
                acc2 = __builtin_amdgcn_mfma_f32_16x16x32_bf16(Al[m][1], bh1.v, acc2, 0, 0, 0);
#pragma unroll
                for (int r = 0; r < 4; ++r) {
                    float u = acc1[r] + acc2[r];       // u' = dot - c2/2 + 0.25 > 0
                    unsigned key = (__float_as_uint(u) & 0xFFFFFFC0u) | ctag;
                    unsigned hi2 = min(k1[m][r], key);
                    k2[m][r] = max(k2[m][r], hi2);
                    k1[m][r] = max(k1[m][r], key);
                }
            }
        }
    }

    // merge + decide, per (m,r): maximize u, tie -> lowest code index
#pragma unroll
    for (int m = 0; m < 2; ++m) {
#pragma unroll
        for (int r = 0; r < 4; ++r) {
            float v1 = __uint_as_float(k1[m][r] & 0xFFFFFFC0u);
            float v2 = __uint_as_float(k2[m][r] & 0xFFFFFFC0u);
            int   b1 = (63 - (int)(k1[m][r] & 63u)) * 16 + col;
#pragma unroll
            for (int d = 1; d < 16; d <<= 1) {
                float o1 = __shfl_xor(v1, d, 64);
                float o2 = __shfl_xor(v2, d, 64);
                int   ob = __shfl_xor(b1, d, 64);
                float n2 = fmaxf(fmaxf(v2, o2), fminf(v1, o1));
                bool take = (o1 > v1) || (o1 == v1 && ob < b1);
                v1 = fmaxf(v1, o1);
                b1 = take ? ob : b1;
                v2 = n2;
            }
            if (col == 0) {
                int tl = wid * 32 + m * 16 + quad * 4 + r;
                int n  = blk_tok0 + tl;
                int best = b1;
                bool fl = (v1 - v2) < margin_u;
                if (fl) {
                    int pos = atomicAdd(wl_count, 1);
                    if (pos < WLCAP) wl[pos] = n;
                    else { best = exact_best_serial(z, cb, c2, n); fl = false; }
                }
                best_s[tl] = best;
                flag_s[tl] = fl ? 1 : 0;
                if (!fl) atomicAdd(&counts[best], 1);
            }
        }
    }
    __syncthreads();

    // coalesced idx write (flagged slots overwritten later by fixup_apply)
    if (tid < 128) out[IDX_OFF + blk_tok0 + tid] = (float)best_s[tid];

    // epilogue: coalesced z_q / loss for unflagged tokens
    const int sub = tid & 15, grp = tid >> 4;
    double dl = 0.0;
    const float4* zrow = (const float4*)z;
    const float4* crow = (const float4*)cb;
    float4* qrow = (float4*)(out + ZQ_OFF);
#pragma unroll
    for (int p = 0; p < 8; ++p) {
        int tl = p * 16 + grp;
        if (!flag_s[tl]) {
            int n = blk_tok0 + tl;
            float4 z4 = zrow[(size_t)n * 16 + sub];
            float4 c4 = crow[(size_t)best_s[tl] * 16 + sub];
            float dx = c4.x - z4.x, dy = c4.y - z4.y;
            float dz = c4.z - z4.z, dw = c4.w - z4.w;
            float4 q;
            q.x = z4.x + dx; q.y = z4.y + dy;
            q.z = z4.z + dz; q.w = z4.w + dw;
            qrow[(size_t)n * 16 + sub] = q;
            dl += (double)dx * dx + (double)dy * dy
                + (double)dz * dz + (double)dw * dw;
        }
    }
#pragma unroll
    for (int off = 32; off > 0; off >>= 1)
        dl += __shfl_down(dl, off, 64);
    if (lane == 0) wred[wid] = dl;
    __syncthreads();
    if (tid == 0)
        atomicAdd(sum_sq, wred[0] + wred[1] + wred[2] + wred[3]);
}

// Scan: one wave per (64-token group x 32-code slice); token-per-lane,
// wave-uniform cb rows. z2 (numpy pairwise) computed inline from exact z.
__global__ __launch_bounds__(64) void fixup_scan(
    const float* __restrict__ z, const float* __restrict__ cb,
    const float* __restrict__ c2, const int* __restrict__ wl,
    const int* __restrict__ wl_count, u64* __restrict__ keys) {

    int count = *wl_count; if (count > WLCAP) count = WLCAP;
    const int g = blockIdx.x >> 5;        // token group (64 per group)
    const int s = blockIdx.x & 31;        // code slice (32 codes)
    if (g * 64 >= count) return;
    const int lane = threadIdx.x;
    const int w = g * 64 + lane;
    const bool valid = w < count;
    const int n = wl[valid ? w : g * 64];

    double zd[E_DIM];
    const float4* zp = (const float4*)(z + (size_t)n * E_DIM);
#pragma unroll
    for (int k = 0; k < 16; ++k) {
        float4 v = zp[k];
        zd[4 * k]     = (double)v.x;
        zd[4 * k + 1] = (double)v.y;
        zd[4 * k + 2] = (double)v.z;
        zd[4 * k + 3] = (double)v.w;
    }
    // numpy-pairwise z2 in f32 (8 accumulators + tree); (float)zd is exact
    float r8[8];
#pragma unroll
    for (int j = 0; j < 8; ++j) {
        float f = (float)zd[j];
        r8[j] = __fmul_rn(f, f);
    }
#pragma unroll
    for (int i = 8; i < 64; i += 8)
#pragma unroll
        for (int j = 0; j < 8; ++j) {
            float f = (float)zd[i + j];
            r8[j] = __fadd_rn(r8[j], __fmul_rn(f, f));
        }
    const float z2 = __fadd_rn(
        __fadd_rn(__fadd_rn(r8[0], r8[1]), __fadd_rn(r8[2], r8[3])),
        __fadd_rn(__fadd_rn(r8[4], r8[5]), __fadd_rn(r8[6], r8[7])));

    u64 best = ~0ull;
    const int e0 = s * 32;
    for (int e = e0; e < e0 + 32; ++e) {
        const float* cp = cb + (size_t)e * E_DIM;   // wave-uniform row
        double m = 0.0;
#pragma unroll
        for (int i = 0; i < E_DIM; ++i)
            m = fma(zd[i], (double)cp[i], m);
        float d = __fsub_rn(__fadd_rn(z2, c2[e]), __fmul_rn(2.0f, (float)m));
        u64 key = ((u64)__float_as_uint(d) << 32) | (unsigned)e;
        if (key < best) best = key;
    }
    if (valid) atomicMin(&keys[w], best);
}

// Apply: one wave per worklist token; finish zq/idx/counts/sum_sq.
__global__ __launch_bounds__(256) void fixup_apply(
    const float* __restrict__ z, const float* __restrict__ cb,
    const int* __restrict__ wl, const int* __restrict__ wl_count,
    const u64* __restrict__ keys, int* __restrict__ counts,
    double* __restrict__ sum_sq, float* __restrict__ out) {

    int count = *wl_count; if (count > WLCAP) count = WLCAP;
    const int lane = threadIdx.x & 63;
    const int gw = blockIdx.x * 4 + (threadIdx.x >> 6);
    for (int w = gw; w < count; w += 1024) {
        const int n = wl[w];
        const int best = (int)(keys[w] & 0xffffffffull);
        float cv = cb[(size_t)best * E_DIM + lane];
        float zi = z[(size_t)n * E_DIM + lane];
        float diff = cv - zi;
        out[ZQ_OFF + (size_t)n * E_DIM + lane] = zi + diff;
        double d2 = (double)diff * (double)diff;
#pragma unroll
        for (int off = 32; off > 0; off >>= 1)
            d2 += __shfl_down(d2, off, 64);
        if (lane == 0) {
            atomicAdd(sum_sq, d2);
            atomicAdd(&counts[best], 1);
            out[IDX_OFF + n] = (float)best;
        }
    }
}

__global__ __launch_bounds__(1024) void finalize_kernel(
    const int* __restrict__ counts, const double* __restrict__ sum_sq,
    float* __restrict__ out) {
    __shared__ double red[1024];
    int e = threadIdx.x;
    double em = (double)counts[e] / (double)N_TOK;
    red[e] = -em * log(em + 1e-10);
    __syncthreads();
    for (int s = 512; s > 0; s >>= 1) {
        if (e < s) red[e] += red[e + s];
        __syncthreads();
    }
    if (e == 0) {
        double usage = red[0];
        double mse = sum_sq[0] / (double)((size_t)N_TOK * E_DIM);
        out[LOSS_OFF] = (float)((1.0 + BETA) * mse + 0.01 * usage);
        out[PERP_OFF] = (float)exp(usage);
    }
}

extern "C" void kernel_launch(void* const* d_in, const int* in_sizes, int n_in,
                              void* d_out, int out_size, void* d_ws, size_t ws_size,
                              hipStream_t stream) {
    const float* z  = (const float*)d_in[0];
    const float* cb = (const float*)d_in[1];
    float* out = (float*)d_out;

    float*          c2     = (float*)((char*)d_ws + WS_C2);
    int*            counts = (int*)((char*)d_ws + WS_CNT);
    double*         sum_sq = (double*)((char*)d_ws + WS_SSQ);
    int*            wlc    = (int*)((char*)d_ws + WS_WLC);
    unsigned short* fhi    = (unsigned short*)((char*)d_ws + WS_FHI);
    unsigned short* flo    = (unsigned short*)((char*)d_ws + WS_FLO);
    int*            wl     = (int*)((char*)d_ws + WS_WL);
    u64*            keys   = (u64*)((char*)d_ws + WS_KEYS);

    // u-space margin = t-space 4.5e-5 / 2 (validated in rounds 2-5)
    float margin_u = (ws_size >= (size_t)(WS_KEYS + 8 * WLCAP)) ? 2.25e-5f : 0.0f;

    c2_kernel<<<4, 256, 0, stream>>>(cb, c2, counts, wlc, sum_sq);
    frag_kernel<<<256, 256, 0, stream>>>(cb, fhi, flo, keys);
    vq_main<<<1024, 256, 0, stream>>>(z, cb, c2, fhi, flo, counts, sum_sq,
                                      wlc, wl, margin_u, out);
    fixup_scan<<<4096, 64, 0, stream>>>(z, cb, c2, wl, wlc, keys);
    fixup_apply<<<256, 256, 0, stream>>>(z, cb, wl, wlc, keys, counts,
                                         sum_sq, out);
    finalize_kernel<<<1, 1024, 0, stream>>>(counts, sum_sq, out);
}